// Round 7
// baseline (249.976 us; speedup 1.0000x reference)
//
#include <hip/hip_runtime.h>
#include <hip/hip_bf16.h>
#include <hip/hip_fp16.h>
#include <math.h>

#define B_ 8
#define Q_ 150
#define QP_ 160     // padded Q for MFMA (10 m-tiles of 16)
#define C_ 134
#define T_ 32
#define H_ 160
#define W_ 160
#define P_ 12544
#define HW_ (H_ * W_)
#define HW4_ (HW_ / 4)

#define SBLK 1024           // sampler block size
#define SBATCH 3            // 3 iters x 4 points x 1024 threads = 12288
#define STAIL 256           // 12544 - 12288
// GEMM
#define SEG_ 56
#define KSEG 224            // P_/SEG_
#define KITER 7             // KSEG/32
#define DSTRIDE (2 * B_ * QP_ * T_)   // 81920 floats per segment slab

// dynamic LDS: imgE[HW] fp16, imgO[HW] fp16 (shifted by one texel), red[32] f32
#define LDS_BYTES (2 * HW_ * 2 + 128)
#define ODD_BASE (2 * HW_)   // byte offset of imgO

typedef __attribute__((ext_vector_type(8))) _Float16 half8;
typedef __attribute__((ext_vector_type(2))) _Float16 half2v;
typedef __attribute__((ext_vector_type(4))) float floatx4;

struct Samp {
  int i00, i01, i10, i11;
  float w00, w01, w10, w11;
};

__device__ __forceinline__ Samp make_samp(float cx, float cy) {
  float x = cx * (float)W_ - 0.5f;
  float y = cy * (float)H_ - 0.5f;
  float x0f = floorf(x), y0f = floorf(y);
  float tx = x - x0f, ty = y - y0f;
  int x0 = (int)x0f, y0 = (int)y0f;
  int x1 = x0 + 1, y1 = y0 + 1;
  bool vx0 = (x0 >= 0) && (x0 < W_);
  bool vx1 = (x1 >= 0) && (x1 < W_);
  bool vy0 = (y0 >= 0) && (y0 < H_);
  bool vy1 = (y1 >= 0) && (y1 < H_);
  int cx0 = min(max(x0, 0), W_ - 1), cx1 = min(max(x1, 0), W_ - 1);
  int cy0 = min(max(y0, 0), H_ - 1), cy1 = min(max(y1, 0), H_ - 1);
  Samp s;
  s.i00 = cy0 * W_ + cx0;
  s.i01 = cy0 * W_ + cx1;
  s.i10 = cy1 * W_ + cx0;
  s.i11 = cy1 * W_ + cx1;
  float w00 = (1.f - tx) * (1.f - ty);
  float w01 = tx * (1.f - ty);
  float w10 = (1.f - tx) * ty;
  float w11 = tx * ty;
  s.w00 = (vx0 && vy0) ? w00 : 0.f;
  s.w01 = (vx1 && vy0) ? w01 : 0.f;
  s.w10 = (vx0 && vy1) ? w10 : 0.f;
  s.w11 = (vx1 && vy1) ? w11 : 0.f;
  return s;
}

__device__ __forceinline__ float waveSum(float v) {
#pragma unroll
  for (int m = 32; m >= 1; m >>= 1) v += __shfl_xor(v, m, 64);
  return v;
}
__device__ __forceinline__ float waveMax(float v) {
#pragma unroll
  for (int m = 32; m >= 1; m >>= 1) v = fmaxf(v, __shfl_xor(v, m, 64));
  return v;
}

__device__ __forceinline__ float h2f(unsigned short u) {
  union { __half h; unsigned short u; } cv;
  cv.u = u;
  return __half2float(cv.h);
}
__device__ __forceinline__ unsigned short f2h(float x) {
  union { __half h; unsigned short u; } cv;
  cv.h = __float2half(x);
  return cv.u;
}

__device__ __forceinline__ float dot2h(unsigned int pv, unsigned int wv,
                                       float acc) {
#if __has_builtin(__builtin_amdgcn_fdot2)
  return __builtin_amdgcn_fdot2(__builtin_bit_cast(half2v, pv),
                                __builtin_bit_cast(half2v, wv), acc, false);
#else
  return acc + h2f(pv & 0xffff) * h2f(wv & 0xffff) +
         h2f(pv >> 16) * h2f(wv >> 16);
#endif
}

// ---------------- phase 0: precompute packed bilinear coeffs per (b,p)
// x-clamp folded into weights: when i01==i00 the pair-read's second texel
// gets weight 0 and w01 merges into w00 (same for row1).
__launch_bounds__(256) __global__
void samp_kernel(const float* __restrict__ coords,
                 unsigned int* __restrict__ sIdx,
                 uint2* __restrict__ sW) {
  int i = blockIdx.x * 256 + threadIdx.x;  // over B_*P_
  float2 cc = ((const float2*)coords)[i];
  Samp s = make_samp(cc.x, cc.y);
  bool dx = (s.i01 != s.i00);
  int dy = (s.i10 != s.i00) ? 1 : 0;
  float w00e = dx ? s.w00 : (s.w00 + s.w01);
  float w01e = dx ? s.w01 : 0.f;
  float w10e = dx ? s.w10 : (s.w10 + s.w11);
  float w11e = dx ? s.w11 : 0.f;
  sIdx[i] = (unsigned)s.i00 | ((unsigned)dy << 16);
  uint2 w;
  w.x = (unsigned)f2h(w00e) | ((unsigned)f2h(w01e) << 16);
  w.y = (unsigned)f2h(w10e) | ((unsigned)f2h(w11e) << 16);
  sW[i] = w;
}

// 2 aligned ds_read_b32 + 2 fdot2 per point.
__device__ __forceinline__ float lds_sample(const char* lds, unsigned iv,
                                            uint2 wv) {
  int i00 = iv & 0xffff & 0x7fff;
  int odd = i00 & 1;
  int off = 2 * i00 + (odd ? (ODD_BASE - 2) : 0);
  int ir2 = (iv & 0x10000) ? (2 * W_) : 0;
  unsigned pair0 = *(const unsigned*)(lds + off);
  unsigned pair1 = *(const unsigned*)(lds + off + ir2);
  return dot2h(pair0, wv.x, dot2h(pair1, wv.y, 0.f));
}

// ---------------- phase 1+2 fused: sample pm (x<Q_) or tm (x>=Q_)
__launch_bounds__(SBLK, 4) __global__
void sample_kernel(const float* __restrict__ masks_q,
                   const float* __restrict__ mask_labels,
                   const unsigned int* __restrict__ sIdx,
                   const uint2* __restrict__ sW,
                   unsigned short* __restrict__ pmh,
                   unsigned short* __restrict__ tmh,
                   float* __restrict__ S_sp, float* __restrict__ S_sig,
                   float* __restrict__ S_tm) {
  extern __shared__ char lds[];
  unsigned short* imgE = (unsigned short*)lds;
  unsigned short* imgO = (unsigned short*)(lds + ODD_BASE);
  float* red = (float*)(lds + 2 * ODD_BASE);

  const int x = blockIdx.x;
  const int b = blockIdx.y;
  const int tid = threadIdx.x;
  const bool isPm = (x < Q_);

  const float* src = isPm ? (masks_q + ((size_t)b * Q_ + x) * HW_)
                          : (mask_labels + ((size_t)b * T_ + (x - Q_)) * HW_);
  const float4* s4 = (const float4*)src;

  // stage: imgE[j]=img[j], imgO[j]=img[j+1] (fp16), both 8B-aligned writes
#pragma unroll
  for (int c = 0; c < 7; ++c) {
    int i = c * SBLK + tid;
    if (c < 6 || tid < HW4_ - 6 * SBLK) {
      float4 v = s4[i];
      float nxt = (i < HW4_ - 1) ? src[4 * i + 4] : 0.f;
      ushort4 e, o;
      e.x = f2h(v.x); e.y = f2h(v.y); e.z = f2h(v.z); e.w = f2h(v.w);
      o.x = e.y; o.y = e.z; o.z = e.w; o.w = f2h(nxt);
      *(ushort4*)&imgE[4 * i] = e;
      *(ushort4*)&imgO[4 * i] = o;
    }
  }
  __syncthreads();

  const unsigned int* sIdxB = sIdx + (size_t)b * P_;
  const uint2* sWB = sW + (size_t)b * P_;

  if (isPm) {
    unsigned short* dst = pmh + ((size_t)b * QP_ + x) * P_;
    float ssp = 0.f, ssg = 0.f;
    for (int c = 0; c < SBATCH; ++c) {
      int p = c * (4 * SBLK) + tid;
      unsigned iv[4];
      uint2 wv[4];
      float v[4];
#pragma unroll
      for (int j = 0; j < 4; ++j) {
        iv[j] = sIdxB[p + j * SBLK];
        wv[j] = sWB[p + j * SBLK];
      }
#pragma unroll
      for (int j = 0; j < 4; ++j) v[j] = lds_sample(lds, iv[j], wv[j]);
#pragma unroll
      for (int j = 0; j < 4; ++j) {
        float pm = v[j];
        float e = __expf(-fabsf(pm));
        float r = __builtin_amdgcn_rcpf(1.f + e);
        float sp = fmaxf(pm, 0.f) - __logf(r);
        float sg = (pm >= 0.f) ? r : e * r;
        ssp += sp;
        ssg += sg;
        dst[p + j * SBLK] = f2h(pm);
      }
    }
    if (tid < STAIL) {
      int p = SBATCH * 4 * SBLK + tid;
      float pm = lds_sample(lds, sIdxB[p], sWB[p]);
      float e = __expf(-fabsf(pm));
      float r = __builtin_amdgcn_rcpf(1.f + e);
      float sp = fmaxf(pm, 0.f) - __logf(r);
      float sg = (pm >= 0.f) ? r : e * r;
      ssp += sp;
      ssg += sg;
      dst[p] = f2h(pm);
    }
    ssp = waveSum(ssp);
    ssg = waveSum(ssg);
    int w = tid >> 6;
    if ((tid & 63) == 0) {
      red[w] = ssp;
      red[16 + w] = ssg;
    }
    __syncthreads();
    if (tid == 0) {
      float a = 0.f, bb = 0.f;
#pragma unroll
      for (int i = 0; i < 16; ++i) { a += red[i]; bb += red[16 + i]; }
      S_sp[b * Q_ + x] = a;
      S_sig[b * Q_ + x] = bb;
    }
  } else {
    const int t = x - Q_;
    unsigned short* dst = tmh + ((size_t)b * T_ + t) * P_;
    float stm = 0.f;
    for (int c = 0; c < SBATCH; ++c) {
      int p = c * (4 * SBLK) + tid;
      unsigned iv[4];
      uint2 wv[4];
#pragma unroll
      for (int j = 0; j < 4; ++j) {
        iv[j] = sIdxB[p + j * SBLK];
        wv[j] = sWB[p + j * SBLK];
      }
#pragma unroll
      for (int j = 0; j < 4; ++j) {
        float v = lds_sample(lds, iv[j], wv[j]);
        stm += v;
        dst[p + j * SBLK] = f2h(v);
      }
    }
    if (tid < STAIL) {
      int p = SBATCH * 4 * SBLK + tid;
      float v = lds_sample(lds, sIdxB[p], sWB[p]);
      stm += v;
      dst[p] = f2h(v);
    }
    stm = waveSum(stm);
    int w = tid >> 6;
    if ((tid & 63) == 0) red[w] = stm;
    __syncthreads();
    if (tid == 0) {
      float a = 0.f;
#pragma unroll
      for (int i = 0; i < 16; ++i) a += red[i];
      S_tm[b * T_ + t] = a;
    }
  }
}

// convert a pm fp16 A-frag to a sigmoid(pm) fp16 A-frag, elementwise
__device__ __forceinline__ half8 sig_frag(half8 a) {
  half8 out;
#pragma unroll
  for (int j = 0; j < 8; ++j) {
    float x = (float)a[j];
    float e = __expf(-fabsf(x));
    float r = __builtin_amdgcn_rcpf(1.f + e);
    float sg = (x >= 0.f) ? r : e * r;
    out[j] = (_Float16)sg;
  }
  return out;
}

// ---------------- phase 3: K-split MFMA GEMM (f16), atomic-free partials.
__launch_bounds__(320) __global__
void gemm_kernel(const unsigned short* __restrict__ pmh,
                 const unsigned short* __restrict__ tmh,
                 float* __restrict__ accP) {
  const int b = blockIdx.y;
  const int seg = blockIdx.x;
  const int w = threadIdx.x >> 6;
  const int l = threadIdx.x & 63;
  const int quad = l >> 4;
  const int mrow = l & 15;

  const unsigned short* pmb = pmh + ((size_t)b * QP_ + w * 32) * P_;
  const unsigned short* tmb = tmh + (size_t)b * T_ * P_;

  floatx4 aL[2][2];
  floatx4 aS[2][2];
#pragma unroll
  for (int i = 0; i < 2; ++i)
#pragma unroll
    for (int j = 0; j < 2; ++j) {
      aL[i][j] = (floatx4){0.f, 0.f, 0.f, 0.f};
      aS[i][j] = (floatx4){0.f, 0.f, 0.f, 0.f};
    }

  const int kbase = seg * KSEG;
#pragma unroll
  for (int ki = 0; ki < KITER; ++ki) {
    const int k0 = kbase + ki * 32 + quad * 8;
    half8 a0 = *(const half8*)(pmb + (size_t)(0 * 16 + mrow) * P_ + k0);
    half8 a1 = *(const half8*)(pmb + (size_t)(1 * 16 + mrow) * P_ + k0);
    half8 b0 = *(const half8*)(tmb + (size_t)(0 * 16 + mrow) * P_ + k0);
    half8 b1 = *(const half8*)(tmb + (size_t)(1 * 16 + mrow) * P_ + k0);
    half8 s0 = sig_frag(a0);
    half8 s1 = sig_frag(a1);
    aL[0][0] = __builtin_amdgcn_mfma_f32_16x16x32_f16(a0, b0, aL[0][0], 0, 0, 0);
    aL[0][1] = __builtin_amdgcn_mfma_f32_16x16x32_f16(a0, b1, aL[0][1], 0, 0, 0);
    aL[1][0] = __builtin_amdgcn_mfma_f32_16x16x32_f16(a1, b0, aL[1][0], 0, 0, 0);
    aL[1][1] = __builtin_amdgcn_mfma_f32_16x16x32_f16(a1, b1, aL[1][1], 0, 0, 0);
    aS[0][0] = __builtin_amdgcn_mfma_f32_16x16x32_f16(s0, b0, aS[0][0], 0, 0, 0);
    aS[0][1] = __builtin_amdgcn_mfma_f32_16x16x32_f16(s0, b1, aS[0][1], 0, 0, 0);
    aS[1][0] = __builtin_amdgcn_mfma_f32_16x16x32_f16(s1, b0, aS[1][0], 0, 0, 0);
    aS[1][1] = __builtin_amdgcn_mfma_f32_16x16x32_f16(s1, b1, aS[1][1], 0, 0, 0);
  }

  float* base = accP + (size_t)seg * DSTRIDE;
#pragma unroll
  for (int mtl = 0; mtl < 2; ++mtl)
#pragma unroll
    for (int nt = 0; nt < 2; ++nt)
#pragma unroll
      for (int r = 0; r < 4; ++r) {
        int q = w * 32 + mtl * 16 + quad * 4 + r;
        int t = nt * 16 + mrow;
        base[((size_t)(0 * B_ + b) * QP_ + q) * T_ + t] = aL[mtl][nt][r];
        base[((size_t)(1 * B_ + b) * QP_ + q) * T_ + t] = aS[mtl][nt][r];
      }
}

// ---------------- phase 3b: reduce partials over segments
__launch_bounds__(256) __global__
void reduce_kernel(const float* __restrict__ accP, float* __restrict__ accD) {
  int i = blockIdx.x * 256 + threadIdx.x;  // < DSTRIDE
  float s = 0.f;
#pragma unroll
  for (int seg = 0; seg < SEG_; ++seg) s += accP[(size_t)seg * DSTRIDE + i];
  accD[i] = s;
}

// ---------------- phase 4: finalize. one wave per (b,q)
__launch_bounds__(64) __global__
void final_kernel(const float* __restrict__ class_q,
                  const int* __restrict__ labels,
                  const float* __restrict__ accD,
                  const float* __restrict__ S_sp,
                  const float* __restrict__ S_sig,
                  const float* __restrict__ S_tm,
                  float* __restrict__ out) {
  const int bq = blockIdx.x;
  const int b = bq / Q_;
  const int q = bq % Q_;
  const int l = threadIdx.x;
  const float* cl = class_q + (size_t)bq * C_;

  float v = -INFINITY;
  for (int c = l; c < C_; c += 64) v = fmaxf(v, cl[c]);
  float m = waveMax(v);
  float e = 0.f;
  for (int c = l; c < C_; c += 64) e += __expf(cl[c] - m);
  float den = waveSum(e);

  if (l < T_) {
    int t = l;
    int lbl = labels[b * T_ + t];
    float prob = __expf(cl[lbl] - m) / den;
    float Dlin = accD[((size_t)(0 * B_ + b) * QP_ + q) * T_ + t];
    float Dsig = accD[((size_t)(1 * B_ + b) * QP_ + q) * T_ + t];
    float cmask = (S_sp[bq] - Dlin) * (1.f / (float)P_);
    float dice = 1.f - (2.f * Dsig + 1.f) / (S_sig[bq] + S_tm[b * T_ + t] + 1.f);
    out[(size_t)bq * T_ + t] = 5.f * cmask + 5.f * dice - prob;
  }
}

extern "C" void kernel_launch(void* const* d_in, const int* in_sizes, int n_in,
                              void* d_out, int out_size, void* d_ws,
                              size_t ws_size, hipStream_t stream) {
  const float* masks_q = (const float*)d_in[0];      // [B,Q,H,W]
  const float* class_q = (const float*)d_in[1];      // [B,Q,C]
  const float* mask_labels = (const float*)d_in[2];  // [B,T,H,W]
  const int* class_labels = (const int*)d_in[3];     // [B,T]
  const float* coords = (const float*)d_in[4];       // [B,P,2]
  float* out = (float*)d_out;

  // ws layout
  float* accD = (float*)d_ws;                         // [2][B][QP_][T_]
  float* accP = accD + DSTRIDE;                       // [SEG_][2][B][QP_][T_]
  uint2* sW = (uint2*)(accP + (size_t)SEG_ * DSTRIDE);  // [B*P]
  unsigned int* sIdx = (unsigned int*)(sW + (size_t)B_ * P_);  // [B*P]
  float* S_sp = (float*)(sIdx + (size_t)B_ * P_);     // [B*Q]
  float* S_sig = S_sp + B_ * Q_;                      // [B*Q]
  float* S_tm = S_sig + B_ * Q_;                      // [B*T]
  unsigned short* pmh = (unsigned short*)(S_tm + B_ * T_);  // [B][QP_][P] fp16
  unsigned short* tmh = pmh + (size_t)B_ * QP_ * P_;        // [B][T][P] fp16

  static int lds_configured = 0;
  (void)lds_configured;
  hipFuncSetAttribute((const void*)sample_kernel,
                      hipFuncAttributeMaxDynamicSharedMemorySize, LDS_BYTES);

  samp_kernel<<<(B_ * P_) / 256, 256, 0, stream>>>(coords, sIdx, sW);
  sample_kernel<<<dim3(Q_ + T_, B_), SBLK, LDS_BYTES, stream>>>(
      masks_q, mask_labels, sIdx, sW, pmh, tmh, S_sp, S_sig, S_tm);
  gemm_kernel<<<dim3(SEG_, B_), 320, 0, stream>>>(pmh, tmh, accP);
  reduce_kernel<<<DSTRIDE / 256, 256, 0, stream>>>(accP, accD);
  final_kernel<<<B_ * Q_, 64, 0, stream>>>(class_q, class_labels, accD, S_sp,
                                           S_sig, S_tm, out);
}